// Round 12
// baseline (20242.381 us; speedup 1.0000x reference)
//
#include <hip/hip_runtime.h>

#define BSZ 64
#define SLEN 32
#define HID 128
#define VOC 96
#define DEPTH 500
#define TPB 64              // ONE wave per block, one block per batch row
#define EPSV 1e-6f
#define RWP 132             // padded row stride of rwT (floats), 16B-aligned

typedef __attribute__((ext_vector_type(2))) float f32x2;

#if defined(__has_builtin)
#if __has_builtin(__builtin_elementwise_fma)
#define VFMA(a, b, c) __builtin_elementwise_fma((a), (b), (c))
#endif
#endif
#ifndef VFMA
__device__ __forceinline__ f32x2 vfma_(f32x2 a, f32x2 b, f32x2 c) {
    f32x2 r; r.x = fmaf(a.x, b.x, c.x); r.y = fmaf(a.y, b.y, c.y); return r;
}
#define VFMA(a, b, c) vfma_((a), (b), (c))
#endif

__device__ __forceinline__ float rsq_fast(float x) {
    float r; asm("v_rsq_f32 %0, %1" : "=v"(r) : "v"(x)); return r;
}

// DPP helpers (ctrl is a compile-time template constant).
template <int CTRL>
__device__ __forceinline__ float qperm(float v) {
    return __int_as_float(__builtin_amdgcn_update_dpp(
        0, __float_as_int(v), CTRL, 0xF, 0xF, true));
}
// full 64-lane sum, every lane gets the total:
// xor1,xor2 (quad_perm), xor4 (row_half_mirror), xor8 (row_mirror) — pure DPP;
// xor16 via ds_swizzle BitMode; xor32 via shfl (ds_bpermute).
#define BFLY64(v)                                                              \
    v += qperm<0xB1>(v);                                                       \
    v += qperm<0x4E>(v);                                                       \
    v += qperm<0x141>(v);                                                      \
    v += qperm<0x140>(v);                                                      \
    v += __int_as_float(__builtin_amdgcn_ds_swizzle(__float_as_int(v), 0x401F)); \
    v += __shfl_xor(v, 32, 64);

__global__ __launch_bounds__(TPB, 1) void rnn_char_lm(
    const int* __restrict__ chars, const float* __restrict__ hidden,
    const float* __restrict__ embed_w, const float* __restrict__ W_g,
    const float* __restrict__ b_g, const float* __restrict__ pre_s,
    const float* __restrict__ post_s, const float* __restrict__ rw_g,
    const float* __restrict__ rb_g, float* __restrict__ out)
{
    __shared__ __align__(16) float hstore[HID];        // the h vector (single buffer)
    __shared__ __align__(16) float rwT[HID * RWP];     // rw[v][k] * post_s[k]; rows 96..127 zero

    const int b = blockIdx.x;
    const int lane = threadIdx.x;   // single wave: 0..63

    // one-time: stage readout rows (post_scale folded); zero the 32 pad rows
    for (int e = lane; e < HID * HID; e += TPB) {
        int v = e >> 7, k = e & (HID - 1);
        rwT[v * RWP + k] = (v < VOC) ? post_s[k] * rw_g[v * HID + k] : 0.0f;
    }

    // one-time: W' = pre_scale[k]*W[k][col] for cols lane and lane+64,
    // packed over k-pairs. 128 f32x2 = 256 VGPRs (1 wave/SIMD budget).
    f32x2 WA[64], WB[64];
#pragma unroll
    for (int q = 0; q < 64; ++q) {
        const float p0 = pre_s[2 * q], p1 = pre_s[2 * q + 1];
        WA[q].x = p0 * W_g[(2 * q) * HID + lane];
        WA[q].y = p1 * W_g[(2 * q + 1) * HID + lane];
        WB[q].x = p0 * W_g[(2 * q) * HID + lane + 64];
        WB[q].y = p1 * W_g[(2 * q + 1) * HID + lane + 64];
    }
    const float bA = b_g[lane], bB = b_g[lane + 64];
    const float psA = post_s[lane], psB = post_s[lane + 64];
    const float rbA = rb_g[lane];
    const float rbB = (lane < VOC - 64) ? rb_g[lane + 64] : 0.0f;

    float hA = hidden[b * HID + lane];
    float hB = hidden[b * HID + lane + 64];
    hstore[lane] = hA;
    hstore[lane + 64] = hB;
    __syncthreads();    // one-time (also covers rwT staging); single wave -> cheap

    for (int t = 0; t < SLEN; ++t) {
        const int c = chars[b * SLEN + t];
        const float evA = embed_w[c * HID + lane] + bA;
        const float evB = embed_w[c * HID + lane + 64] + bB;

#pragma unroll 1
        for (int it = 0; it < DEPTH; ++it) {
            // sumsq from OWN h values; butterfly latency overlaps the dot below
            float ss = fmaf(hA, hA, hB * hB);
            BFLY64(ss)
            const float rn = rsq_fast(fmaf(ss, 1.0f / HID, EPSV));

            // full-k dot for both columns, h broadcast-read from LDS.
            // adjacent-pair extraction (x.x,x.y)/(x.z,x.w) -> v_pk_fma_f32.
            const float4* hb = (const float4*)hstore;
            f32x2 aA0 = {0, 0}, aA1 = {0, 0}, aB0 = {0, 0}, aB1 = {0, 0};
#pragma unroll
            for (int i = 0; i < 32; ++i) {
                const float4 x = hb[i];
                f32x2 lo; lo.x = x.x; lo.y = x.y;
                f32x2 hi; hi.x = x.z; hi.y = x.w;
                aA0 = VFMA(lo, WA[2 * i], aA0);
                aA1 = VFMA(hi, WA[2 * i + 1], aA1);
                aB0 = VFMA(lo, WB[2 * i], aB0);
                aB1 = VFMA(hi, WB[2 * i + 1], aB1);
            }
            const float yA = (aA0.x + aA0.y) + (aA1.x + aA1.y);
            const float yB = (aB0.x + aB0.y) + (aB1.x + aB1.y);
            hA += fmaxf(fmaf(yA, rn, evA), 0.0f);
            hB += fmaxf(fmaf(yB, rn, evB), 0.0f);
            // in-wave DS ordering + compiler lgkmcnt make this visible to the
            // next iteration's reads; no barrier (single wave).
            hstore[lane] = hA;
            hstore[lane + 64] = hB;
        }

        // ---- epilogue: post-norm (replaces h) + readout ----
        {
            float ss = fmaf(hA, hA, hB * hB);
            BFLY64(ss)
            const float rnp = 1.0f / sqrtf(ss * (1.0f / HID) + EPSV);

            // readout dots from RAW h (pre-norm) still in hstore; post_s is
            // folded into rwT, rnp applied at the end.
            const float4* hr = (const float4*)hstore;
            const float4* w1 = (const float4*)&rwT[lane * RWP];
            const float4* w2 = (const float4*)&rwT[(lane + 64) * RWP];
            f32x2 a1 = {0, 0}, a2 = {0, 0};
#pragma unroll
            for (int i = 0; i < 32; ++i) {
                const float4 x = hr[i];
                const float4 u = w1[i];
                const float4 v = w2[i];
                f32x2 lo; lo.x = x.x; lo.y = x.y;
                f32x2 hi; hi.x = x.z; hi.y = x.w;
                f32x2 ul; ul.x = u.x; ul.y = u.y;
                f32x2 uh; uh.x = u.z; uh.y = u.w;
                f32x2 vl; vl.x = v.x; vl.y = v.y;
                f32x2 vh; vh.x = v.z; vh.y = v.w;
                a1 = VFMA(lo, ul, a1);
                a1 = VFMA(hi, uh, a1);
                a2 = VFMA(lo, vl, a2);
                a2 = VFMA(hi, vh, a2);
            }
            const float l1 = a1.x + a1.y;
            const float l2 = a2.x + a2.y;

            // carried state = post-normed h; write back for next timestep
            hA *= rnp * psA;
            hB *= rnp * psB;
            hstore[lane] = hA;          // after the hr reads (program order)
            hstore[lane + 64] = hB;

            out[(b * SLEN + t) * VOC + lane] = fmaf(l1, rnp, rbA);
            if (lane < VOC - 64)
                out[(b * SLEN + t) * VOC + 64 + lane] = fmaf(l2, rnp, rbB);
        }
    }

    out[BSZ * SLEN * VOC + b * HID + lane] = hA;
    out[BSZ * SLEN * VOC + b * HID + lane + 64] = hB;
}

extern "C" void kernel_launch(void* const* d_in, const int* in_sizes, int n_in,
                              void* d_out, int out_size, void* d_ws, size_t ws_size,
                              hipStream_t stream)
{
    const int* chars      = (const int*)d_in[0];
    const float* hidden   = (const float*)d_in[1];
    const float* embed_w  = (const float*)d_in[2];
    const float* W_g      = (const float*)d_in[3];
    const float* b_g      = (const float*)d_in[4];
    const float* pre_s    = (const float*)d_in[5];
    const float* post_s   = (const float*)d_in[6];
    const float* rw_g     = (const float*)d_in[7];
    const float* rb_g     = (const float*)d_in[8];
    float* out            = (float*)d_out;

    rnn_char_lm<<<dim3(BSZ), dim3(TPB), 0, stream>>>(
        chars, hidden, embed_w, W_g, b_g, pre_s, post_s, rw_g, rb_g, out);
}

// Round 13
// 8322.779 us; speedup vs baseline: 2.4322x; 2.4322x over previous
//
#include <hip/hip_runtime.h>

#define BSZ 64
#define SLEN 32
#define HID 128
#define VOC 96
#define DEPTH 500
#define TPB 256             // 4 waves; one block per TWO batch rows (skewed)
#define EPSV 1e-6f
#define PAD 20              // floats per 16-float h-chunk (16 data + 4 pad)

typedef __attribute__((ext_vector_type(2))) float f32x2;

#if defined(__has_builtin)
#if __has_builtin(__builtin_elementwise_fma)
#define VFMA(a, b, c) __builtin_elementwise_fma((a), (b), (c))
#endif
#endif
#ifndef VFMA
__device__ __forceinline__ f32x2 vfma_(f32x2 a, f32x2 b, f32x2 c) {
    f32x2 r; r.x = fmaf(a.x, b.x, c.x); r.y = fmaf(a.y, b.y, c.y); return r;
}
#define VFMA(a, b, c) vfma_((a), (b), (c))
#endif

__device__ __forceinline__ float rsq_fast(float x) {
    float r; asm("v_rsq_f32 %0, %1" : "=v"(r) : "v"(x)); return r;
}

// DPP helpers; 0xB1 quad_perm xor1, 0x4E quad_perm xor2, 0x141 row_half_mirror
template <int CTRL>
__device__ __forceinline__ float qperm(float v) {
    return __int_as_float(__builtin_amdgcn_update_dpp(
        0, __float_as_int(v), CTRL, 0xF, 0xF, true));
}
// 8-lane reduction, pure VALU (R8-proven, bit-identical to xor4 finish)
#define BFLY8(v)                                                               \
    v += qperm<0xB1>(v);                                                       \
    v += qperm<0x4E>(v);                                                       \
    v += qperm<0x141>(v);

__global__ __launch_bounds__(TPB, 1) void rnn_char_lm(
    const int* __restrict__ chars, const float* __restrict__ hidden,
    const float* __restrict__ embed_w, const float* __restrict__ W_g,
    const float* __restrict__ b_g, const float* __restrict__ pre_s,
    const float* __restrict__ post_s, const float* __restrict__ rw_g,
    const float* __restrict__ rb_g, float* __restrict__ out)
{
    __shared__ __align__(16) float hbufA[2][8 * PAD];  // row A h staging, dbuf
    __shared__ __align__(16) float hbufB[2][8 * PAD];  // row B h staging, dbuf
    __shared__ float rwT[HID * VOC];                   // readout_w transposed [k][v]

    const int tid = threadIdx.x;
    const int w = tid >> 6;
    const int lane = tid & 63;
    const int g = lane >> 3;          // col-group: 4 consecutive cols
    const int ch = lane & 7;          // k-chunk: 16 k-values

    const int rowA = 2 * blockIdx.x;
    const int rowB = rowA + 1;

    const int col0 = 32 * w + 4 * g;  // lane's 4 cols
    const int widx = PAD * (col0 >> 4) + (col0 & 15);
    const int rbase = PAD * ch;       // lane's read chunk base

    // one-time: stage readout_w transposed into LDS
    for (int e = tid; e < VOC * HID; e += TPB) {
        int v = e >> 7;
        int k = e & (HID - 1);
        rwT[k * VOC + v] = rw_g[e];
    }

    // one-time: W' = pre_scale[k]*W[k][col0+c] (shared by both rows). 64 VGPRs.
    f32x2 W2[4][8];
#pragma unroll
    for (int q = 0; q < 8; ++q) {
        int k0 = 16 * ch + 2 * q;
        float p0 = pre_s[k0], p1 = pre_s[k0 + 1];
#pragma unroll
        for (int c = 0; c < 4; ++c) {
            f32x2 t;
            t.x = p0 * W_g[k0 * HID + col0 + c];
            t.y = p1 * W_g[(k0 + 1) * HID + col0 + c];
            W2[c][q] = t;
        }
    }
    const float4 bv  = *(const float4*)&b_g[col0];
    const float4 psv = *(const float4*)&post_s[col0];
    const float rbv = (tid < VOC) ? rb_g[tid] : 0.0f;

    float4 hcA = *(const float4*)&hidden[rowA * HID + col0];
    float4 hcB = *(const float4*)&hidden[rowB * HID + col0];

    if (ch == 0) {
        *(float4*)&hbufA[0][widx] = hcA;
        *(float4*)&hbufB[0][widx] = hcB;
    }
    __syncthreads();

    // loop-carried staging regs: row A's current h slice
    float4 xa0, xa1, xa2, xa3;
    {
        const float4* rbA = (const float4*)&hbufA[0][rbase];
        xa0 = rbA[0]; xa1 = rbA[1]; xa2 = rbA[2]; xa3 = rbA[3];
    }

#define DOT(x0, x1, x2, x3, a0, a1, a2, a3, s)                                 \
    {                                                                          \
        _Pragma("unroll")                                                      \
        for (int q = 0; q < 8; ++q) {                                          \
            const float4 xq = (q < 2) ? x0 : (q < 4) ? x1 : (q < 6) ? x2 : x3; \
            f32x2 hv;                                                          \
            hv.x = (q & 1) ? xq.z : xq.x;                                      \
            hv.y = (q & 1) ? xq.w : xq.y;                                      \
            s  = VFMA(hv, hv, s);                                              \
            a0 = VFMA(hv, W2[0][q], a0);                                       \
            a1 = VFMA(hv, W2[1][q], a1);                                       \
            a2 = VFMA(hv, W2[2][q], a2);                                       \
            a3 = VFMA(hv, W2[3][q], a3);                                       \
        }                                                                      \
    }

#define FIN(a0, a1, a2, a3, s, hc, ev)                                         \
    {                                                                          \
        float y0 = a0.x + a0.y, y1 = a1.x + a1.y;                              \
        float y2 = a2.x + a2.y, y3 = a3.x + a3.y;                              \
        float ssl = s.x + s.y;                                                 \
        BFLY8(y0) BFLY8(y1) BFLY8(y2) BFLY8(y3) BFLY8(ssl)                     \
        const float rn = rsq_fast(fmaf(ssl, 1.0f / HID, EPSV));                \
        hc.x += fmaxf(fmaf(y0, rn, ev.x), 0.0f);                               \
        hc.y += fmaxf(fmaf(y1, rn, ev.y), 0.0f);                               \
        hc.z += fmaxf(fmaf(y2, rn, ev.z), 0.0f);                               \
        hc.w += fmaxf(fmaf(y3, rn, ev.w), 0.0f);                               \
    }

// one BODY advances BOTH rows, skewed: reads of one row's h issue before the
// other row's VALU chain -> LDS latency hides under compute.
#define BODY(P)                                                                \
    {                                                                          \
        /* half A: prefetch row-B h; advance row A from xa */                  \
        const float4* rbB = (const float4*)&hbufB[P][rbase];                   \
        float4 nb0 = rbB[0], nb1 = rbB[1], nb2 = rbB[2], nb3 = rbB[3];         \
        f32x2 a0={0,0},a1={0,0},a2={0,0},a3={0,0},sa={0,0};                    \
        DOT(xa0, xa1, xa2, xa3, a0, a1, a2, a3, sa)                            \
        FIN(a0, a1, a2, a3, sa, hcA, evA)                                      \
        if (ch == 0) *(float4*)&hbufA[P ^ 1][widx] = hcA;                      \
        __syncthreads();                                                       \
        /* half B: prefetch row-A next h; advance row B from nb */             \
        const float4* rbA = (const float4*)&hbufA[P ^ 1][rbase];               \
        float4 na0 = rbA[0], na1 = rbA[1], na2 = rbA[2], na3 = rbA[3];         \
        f32x2 b0={0,0},b1={0,0},b2={0,0},b3={0,0},sb={0,0};                    \
        DOT(nb0, nb1, nb2, nb3, b0, b1, b2, b3, sb)                            \
        FIN(b0, b1, b2, b3, sb, hcB, evB)                                      \
        if (ch == 0) *(float4*)&hbufB[P ^ 1][widx] = hcB;                      \
        __syncthreads();                                                       \
        xa0 = na0; xa1 = na1; xa2 = na2; xa3 = na3;                            \
    }

    for (int t = 0; t < SLEN; ++t) {
        const int cA = chars[rowA * SLEN + t];
        const int cB = chars[rowB * SLEN + t];
        const float4 erA = *(const float4*)&embed_w[cA * HID + col0];
        const float4 erB = *(const float4*)&embed_w[cB * HID + col0];
        float4 evA, evB;
        evA.x = erA.x + bv.x; evA.y = erA.y + bv.y;
        evA.z = erA.z + bv.z; evA.w = erA.w + bv.w;
        evB.x = erB.x + bv.x; evB.y = erB.y + bv.y;
        evB.z = erB.z + bv.z; evB.w = erB.w + bv.w;

        for (int it = 0; it < DEPTH / 2; ++it) {
            BODY(0)
            BODY(1)
        }
        // 500 advances done; current h in hbufA[0]/hbufB[0]; xa = row-A slice.

        // ---- epilogue: post-norm (replaces h) + readout, both rows ----
        {
            // row-B ss reads issue first; row-A ss from xa already in regs
            const float4* rbB = (const float4*)&hbufB[0][rbase];
            float4 yb0 = rbB[0], yb1 = rbB[1], yb2 = rbB[2], yb3 = rbB[3];
            f32x2 sA = {0, 0}, sB = {0, 0};
            f32x2 hv;
            hv.x = xa0.x; hv.y = xa0.y; sA = VFMA(hv, hv, sA);
            hv.x = xa0.z; hv.y = xa0.w; sA = VFMA(hv, hv, sA);
            hv.x = xa1.x; hv.y = xa1.y; sA = VFMA(hv, hv, sA);
            hv.x = xa1.z; hv.y = xa1.w; sA = VFMA(hv, hv, sA);
            hv.x = xa2.x; hv.y = xa2.y; sA = VFMA(hv, hv, sA);
            hv.x = xa2.z; hv.y = xa2.w; sA = VFMA(hv, hv, sA);
            hv.x = xa3.x; hv.y = xa3.y; sA = VFMA(hv, hv, sA);
            hv.x = xa3.z; hv.y = xa3.w; sA = VFMA(hv, hv, sA);
            hv.x = yb0.x; hv.y = yb0.y; sB = VFMA(hv, hv, sB);
            hv.x = yb0.z; hv.y = yb0.w; sB = VFMA(hv, hv, sB);
            hv.x = yb1.x; hv.y = yb1.y; sB = VFMA(hv, hv, sB);
            hv.x = yb1.z; hv.y = yb1.w; sB = VFMA(hv, hv, sB);
            hv.x = yb2.x; hv.y = yb2.y; sB = VFMA(hv, hv, sB);
            hv.x = yb2.z; hv.y = yb2.w; sB = VFMA(hv, hv, sB);
            hv.x = yb3.x; hv.y = yb3.y; sB = VFMA(hv, hv, sB);
            hv.x = yb3.z; hv.y = yb3.w; sB = VFMA(hv, hv, sB);
            float ssA = sA.x + sA.y, ssB = sB.x + sB.y;
            BFLY8(ssA) BFLY8(ssB)
            const float rnA = 1.0f / sqrtf(ssA * (1.0f / HID) + EPSV);
            const float rnB = 1.0f / sqrtf(ssB * (1.0f / HID) + EPSV);
            hcA.x *= rnA * psv.x; hcA.y *= rnA * psv.y;
            hcA.z *= rnA * psv.z; hcA.w *= rnA * psv.w;
            hcB.x *= rnB * psv.x; hcB.y *= rnB * psv.y;
            hcB.z *= rnB * psv.z; hcB.w *= rnB * psv.w;
            __syncthreads();                         // all ss-reads done
            if (ch == 0) {
                *(float4*)&hbufA[0][widx] = hcA;     // hpost, padded layout
                *(float4*)&hbufB[0][widx] = hcB;
            }
            __syncthreads();                         // visible to readout+reload
        }

        // reload xa (post-normed row-A h) for next timestep's first BODY
        {
            const float4* rbA = (const float4*)&hbufA[0][rbase];
            xa0 = rbA[0]; xa1 = rbA[1]; xa2 = rbA[2]; xa3 = rbA[3];
        }

        if (tid < VOC) {
            float accA0 = 0.0f, accA1 = 0.0f, accB0 = 0.0f, accB1 = 0.0f;
#pragma unroll
            for (int C = 0; C < 8; ++C) {
#pragma unroll
                for (int m4 = 0; m4 < 4; ++m4) {
                    const int k = 16 * C + 4 * m4;
                    const float4 xA = *(const float4*)&hbufA[0][PAD * C + 4 * m4];
                    const float4 xB = *(const float4*)&hbufB[0][PAD * C + 4 * m4];
                    const float w0 = rwT[(k + 0) * VOC + tid];
                    const float w1 = rwT[(k + 1) * VOC + tid];
                    const float w2 = rwT[(k + 2) * VOC + tid];
                    const float w3 = rwT[(k + 3) * VOC + tid];
                    accA0 = fmaf(xA.x, w0, accA0);
                    accA1 = fmaf(xA.y, w1, accA1);
                    accA0 = fmaf(xA.z, w2, accA0);
                    accA1 = fmaf(xA.w, w3, accA1);
                    accB0 = fmaf(xB.x, w0, accB0);
                    accB1 = fmaf(xB.y, w1, accB1);
                    accB0 = fmaf(xB.z, w2, accB0);
                    accB1 = fmaf(xB.w, w3, accB1);
                }
            }
            out[(rowA * SLEN + t) * VOC + tid] = accA0 + accA1 + rbv;
            out[(rowB * SLEN + t) * VOC + tid] = accB0 + accB1 + rbv;
        }
        // next BODY(0) writes hbuf*[1] first (barrier-gated); hbuf*[0] is
        // only read -> no extra barrier needed here.
    }

    if (ch == 0) {
        *(float4*)&out[BSZ * SLEN * VOC + rowA * HID + col0] = hcA;
        *(float4*)&out[BSZ * SLEN * VOC + rowB * HID + col0] = hcB;
    }

#undef BODY
#undef DOT
#undef FIN
}

extern "C" void kernel_launch(void* const* d_in, const int* in_sizes, int n_in,
                              void* d_out, int out_size, void* d_ws, size_t ws_size,
                              hipStream_t stream)
{
    const int* chars      = (const int*)d_in[0];
    const float* hidden   = (const float*)d_in[1];
    const float* embed_w  = (const float*)d_in[2];
    const float* W_g      = (const float*)d_in[3];
    const float* b_g      = (const float*)d_in[4];
    const float* pre_s    = (const float*)d_in[5];
    const float* post_s   = (const float*)d_in[6];
    const float* rw_g     = (const float*)d_in[7];
    const float* rb_g     = (const float*)d_in[8];
    float* out            = (float*)d_out;

    rnn_char_lm<<<dim3(BSZ / 2), dim3(TPB), 0, stream>>>(
        chars, hidden, embed_w, W_g, b_g, pre_s, post_s, rw_g, rb_g, out);
}

// Round 14
// 5962.639 us; speedup vs baseline: 3.3949x; 1.3958x over previous
//
#include <hip/hip_runtime.h>

#define BSZ 64
#define SLEN 32
#define HID 128
#define VOC 96
#define DEPTH 500
#define TPB 512             // 8 waves: waves 0-3 = row A, waves 4-7 = row B
#define EPSV 1e-6f
#define PAD 20              // floats per 16-float h-chunk (16 data + 4 pad)

typedef __attribute__((ext_vector_type(2))) float f32x2;

#if defined(__has_builtin)
#if __has_builtin(__builtin_elementwise_fma)
#define VFMA(a, b, c) __builtin_elementwise_fma((a), (b), (c))
#endif
#endif
#ifndef VFMA
__device__ __forceinline__ f32x2 vfma_(f32x2 a, f32x2 b, f32x2 c) {
    f32x2 r; r.x = fmaf(a.x, b.x, c.x); r.y = fmaf(a.y, b.y, c.y); return r;
}
#define VFMA(a, b, c) vfma_((a), (b), (c))
#endif

__device__ __forceinline__ float rsq_fast(float x) {
    float r; asm("v_rsq_f32 %0, %1" : "=v"(r) : "v"(x)); return r;
}

// DPP helpers; 0xB1 quad_perm xor1, 0x4E quad_perm xor2, 0x141 row_half_mirror
template <int CTRL>
__device__ __forceinline__ float qperm(float v) {
    return __int_as_float(__builtin_amdgcn_update_dpp(
        0, __float_as_int(v), CTRL, 0xF, 0xF, true));
}
// 8-lane reduction, pure VALU (R8-proven, bit-identical to xor4 finish)
#define BFLY8(v)                                                               \
    v += qperm<0xB1>(v);                                                       \
    v += qperm<0x4E>(v);                                                       \
    v += qperm<0x141>(v);

__global__ __launch_bounds__(TPB, 1) void rnn_char_lm(
    const int* __restrict__ chars, const float* __restrict__ hidden,
    const float* __restrict__ embed_w, const float* __restrict__ W_g,
    const float* __restrict__ b_g, const float* __restrict__ pre_s,
    const float* __restrict__ post_s, const float* __restrict__ rw_g,
    const float* __restrict__ rb_g, float* __restrict__ out)
{
    // [half][parity][chunked h]: two independent R8 pipelines
    __shared__ __align__(16) float hbuf[2][2][8 * PAD];
    __shared__ float rwT[HID * VOC];                  // readout_w transposed [k][v]

    const int tid = threadIdx.x;
    const int w8 = tid >> 6;          // 0..7
    const int half = w8 >> 2;         // 0 = row A, 1 = row B
    const int wl = w8 & 3;            // wave within half (R8's w)
    const int lane = tid & 63;
    const int g = lane >> 3;          // col-group: 4 consecutive cols
    const int ch = lane & 7;          // k-chunk: 16 k-values

    const int row = 2 * blockIdx.x + half;

    const int col0 = 32 * wl + 4 * g; // lane's 4 cols
    const int widx = PAD * (col0 >> 4) + (col0 & 15);
    const int rbase = PAD * ch;       // lane's read chunk base

    // one-time: stage readout_w transposed into LDS (shared by both halves)
    for (int e = tid; e < VOC * HID; e += TPB) {
        int v = e >> 7;
        int k = e & (HID - 1);
        rwT[k * VOC + v] = rw_g[e];
    }

    // one-time: W' = pre_scale[k]*W[k][col0+c], packed over k-pairs. 64 VGPRs.
    f32x2 W2[4][8];
#pragma unroll
    for (int q = 0; q < 8; ++q) {
        int k0 = 16 * ch + 2 * q;
        float p0 = pre_s[k0], p1 = pre_s[k0 + 1];
#pragma unroll
        for (int c = 0; c < 4; ++c) {
            f32x2 t;
            t.x = p0 * W_g[k0 * HID + col0 + c];
            t.y = p1 * W_g[(k0 + 1) * HID + col0 + c];
            W2[c][q] = t;
        }
    }
    const float4 bv  = *(const float4*)&b_g[col0];
    const float4 psv = *(const float4*)&post_s[col0];
    const int vv = tid & 255;                        // readout slot within half
    const float rbv = (vv < VOC) ? rb_g[vv] : 0.0f;

    // h for lane's 4 cols of its row (replicated across the 8 ch-lanes)
    float4 hc = *(const float4*)&hidden[row * HID + col0];

    if (ch == 0) *(float4*)&hbuf[half][0][widx] = hc;   // stage initial h
    __syncthreads();

// one recurrent iteration of THIS half's row at read-parity P.
// The other half's waves run the same code on an independent chain -> the
// CU scheduler interleaves the two chains per SIMD (TLP latency hiding).
#define ITER(P)                                                                \
    {                                                                          \
        const float4* rb = (const float4*)&hbuf[half][P][rbase];               \
        float4 x0 = rb[0], x1 = rb[1], x2 = rb[2], x3 = rb[3];                 \
        f32x2 a0 = {0,0}, a1 = {0,0}, a2 = {0,0}, a3 = {0,0}, s = {0,0};       \
        _Pragma("unroll")                                                      \
        for (int q = 0; q < 8; ++q) {                                          \
            const float4 xq = (q < 2) ? x0 : (q < 4) ? x1 : (q < 6) ? x2 : x3; \
            f32x2 hv;                                                          \
            hv.x = (q & 1) ? xq.z : xq.x;                                      \
            hv.y = (q & 1) ? xq.w : xq.y;                                      \
            s  = VFMA(hv, hv, s);                                              \
            a0 = VFMA(hv, W2[0][q], a0);                                       \
            a1 = VFMA(hv, W2[1][q], a1);                                       \
            a2 = VFMA(hv, W2[2][q], a2);                                       \
            a3 = VFMA(hv, W2[3][q], a3);                                       \
        }                                                                      \
        float y0 = a0.x + a0.y, y1 = a1.x + a1.y;                              \
        float y2 = a2.x + a2.y, y3 = a3.x + a3.y;                              \
        float ssl = s.x + s.y;                                                 \
        BFLY8(y0) BFLY8(y1) BFLY8(y2) BFLY8(y3) BFLY8(ssl)                     \
        const float rn = rsq_fast(fmaf(ssl, 1.0f / HID, EPSV));                \
        hc.x += fmaxf(fmaf(y0, rn, ev.x), 0.0f);                               \
        hc.y += fmaxf(fmaf(y1, rn, ev.y), 0.0f);                               \
        hc.z += fmaxf(fmaf(y2, rn, ev.z), 0.0f);                               \
        hc.w += fmaxf(fmaf(y3, rn, ev.w), 0.0f);                               \
        if (ch == 0) *(float4*)&hbuf[half][P ^ 1][widx] = hc;                  \
        __syncthreads();                                                       \
    }

    for (int t = 0; t < SLEN; ++t) {
        const int c = chars[row * SLEN + t];
        const float4 er = *(const float4*)&embed_w[c * HID + col0];
        float4 ev;
        ev.x = er.x + bv.x; ev.y = er.y + bv.y;
        ev.z = er.z + bv.z; ev.w = er.w + bv.w;

        for (int it = 0; it < DEPTH / 2; ++it) {
            ITER(0)
            ITER(1)
        }
        // after 500 iters, current h sits in hbuf[half][0].

        // ---- epilogue: post-norm (replaces h) + readout ----
        {
            const float4* rb = (const float4*)&hbuf[half][0][rbase];
            float4 x0 = rb[0], x1 = rb[1], x2 = rb[2], x3 = rb[3];
            f32x2 s = {0, 0};
            f32x2 hv;
            hv.x = x0.x; hv.y = x0.y; s = VFMA(hv, hv, s);
            hv.x = x0.z; hv.y = x0.w; s = VFMA(hv, hv, s);
            hv.x = x1.x; hv.y = x1.y; s = VFMA(hv, hv, s);
            hv.x = x1.z; hv.y = x1.w; s = VFMA(hv, hv, s);
            hv.x = x2.x; hv.y = x2.y; s = VFMA(hv, hv, s);
            hv.x = x2.z; hv.y = x2.w; s = VFMA(hv, hv, s);
            hv.x = x3.x; hv.y = x3.y; s = VFMA(hv, hv, s);
            hv.x = x3.z; hv.y = x3.w; s = VFMA(hv, hv, s);
            float ssl = s.x + s.y;
            BFLY8(ssl)
            const float rnp = 1.0f / sqrtf(ssl * (1.0f / HID) + EPSV);
            hc.x *= rnp * psv.x; hc.y *= rnp * psv.y;
            hc.z *= rnp * psv.z; hc.w *= rnp * psv.w;
            __syncthreads();                         // all ss-reads done
            if (ch == 0) *(float4*)&hbuf[half][0][widx] = hc;  // hpost
            __syncthreads();                         // visible to readout+next t
        }

        if (vv < VOC) {
            float acc0 = 0.0f, acc1 = 0.0f;
#pragma unroll
            for (int C = 0; C < 8; ++C) {
#pragma unroll
                for (int m4 = 0; m4 < 4; ++m4) {
                    const float4 x = *(const float4*)&hbuf[half][0][PAD * C + 4 * m4];
                    const int k = 16 * C + 4 * m4;
                    acc0 = fmaf(x.x, rwT[(k + 0) * VOC + vv], acc0);
                    acc1 = fmaf(x.y, rwT[(k + 1) * VOC + vv], acc1);
                    acc0 = fmaf(x.z, rwT[(k + 2) * VOC + vv], acc0);
                    acc1 = fmaf(x.w, rwT[(k + 3) * VOC + vv], acc1);
                }
            }
            out[(row * SLEN + t) * VOC + vv] = acc0 + acc1 + rbv;
        }
        // next t's ITER(0) reads hbuf[half][0] (reads only; its first write
        // goes to hbuf[half][1] and is barrier-gated) -> no extra barrier.
    }

    if (ch == 0)
        *(float4*)&out[BSZ * SLEN * VOC + row * HID + col0] = hc;

#undef ITER
}

extern "C" void kernel_launch(void* const* d_in, const int* in_sizes, int n_in,
                              void* d_out, int out_size, void* d_ws, size_t ws_size,
                              hipStream_t stream)
{
    const int* chars      = (const int*)d_in[0];
    const float* hidden   = (const float*)d_in[1];
    const float* embed_w  = (const float*)d_in[2];
    const float* W_g      = (const float*)d_in[3];
    const float* b_g      = (const float*)d_in[4];
    const float* pre_s    = (const float*)d_in[5];
    const float* post_s   = (const float*)d_in[6];
    const float* rw_g     = (const float*)d_in[7];
    const float* rb_g     = (const float*)d_in[8];
    float* out            = (float*)d_out;

    rnn_char_lm<<<dim3(BSZ / 2), dim3(TPB), 0, stream>>>(
        chars, hidden, embed_w, W_g, b_g, pre_s, post_s, rw_g, rb_g, out);
}

// Round 15
// 4616.140 us; speedup vs baseline: 4.3851x; 1.2917x over previous
//
#include <hip/hip_runtime.h>

#define BSZ 64
#define SLEN 32
#define HID 128
#define VOC 96
#define DEPTH 500
#define TPB 256             // 4 waves per block, one block per batch row
#define EPSV 1e-6f
#define PAD 20              // floats per 16-float h-chunk (16 data + 4 pad)

typedef __attribute__((ext_vector_type(2))) float f32x2;

#if defined(__has_builtin)
#if __has_builtin(__builtin_elementwise_fma)
#define VFMA(a, b, c) __builtin_elementwise_fma((a), (b), (c))
#endif
#endif
#ifndef VFMA
__device__ __forceinline__ f32x2 vfma_(f32x2 a, f32x2 b, f32x2 c) {
    f32x2 r; r.x = fmaf(a.x, b.x, c.x); r.y = fmaf(a.y, b.y, c.y); return r;
}
#define VFMA(a, b, c) vfma_((a), (b), (c))
#endif

__device__ __forceinline__ float rsq_fast(float x) {
    float r; asm("v_rsq_f32 %0, %1" : "=v"(r) : "v"(x)); return r;
}

// DPP helper with row mask (masked-off rows contribute old=0 -> add-identity).
// 0xB1 quad_perm xor1, 0x4E quad_perm xor2, 0x141 row_half_mirror,
// 0x140 row_mirror, 0x142 row_bcast15, 0x143 row_bcast31.
template <int CTRL, int RMASK>
__device__ __forceinline__ float qperm_m(float v) {
    return __int_as_float(__builtin_amdgcn_update_dpp(
        0, __float_as_int(v), CTRL, RMASK, 0xF, true));
}
template <int CTRL>
__device__ __forceinline__ float qperm(float v) { return qperm_m<CTRL, 0xF>(v); }

// 8-lane reduction, pure VALU (R8-proven, bit-identical to xor4 finish)
#define BFLY8(v)                                                               \
    v += qperm<0xB1>(v);                                                       \
    v += qperm<0x4E>(v);                                                       \
    v += qperm<0x141>(v);

// Wave-level sum over the 8 g-groups (input uniform over ch = lane&7, varies
// with g = lane>>3). row_mirror adds the bit-3 partner (rows hold S_r);
// masked bcast15 gives rows 1,3 = S01,S23; masked bcast31 gives row 3 = full.
// Result valid in lanes 48..63; lane 63 is the designated writer.
__device__ __forceinline__ float wave_g_sum(float v) {
    v += qperm_m<0x140, 0xF>(v);
    v += qperm_m<0x142, 0xA>(v);
    v += qperm_m<0x143, 0xC>(v);
    return v;
}

__global__ __launch_bounds__(TPB, 1) void rnn_char_lm(
    const int* __restrict__ chars, const float* __restrict__ hidden,
    const float* __restrict__ embed_w, const float* __restrict__ W_g,
    const float* __restrict__ b_g, const float* __restrict__ pre_s,
    const float* __restrict__ post_s, const float* __restrict__ rw_g,
    const float* __restrict__ rb_g, float* __restrict__ out)
{
    __shared__ __align__(16) float hbuf[2][8 * PAD];  // padded chunked h, dbuf
    __shared__ __align__(16) float ssb[2][4];         // per-wave sumsq partials, dbuf
    __shared__ float rwT[HID * VOC];                  // readout_w transposed [k][v]

    const int b = blockIdx.x;
    const int tid = threadIdx.x;
    const int w = tid >> 6;
    const int lane = tid & 63;
    const int g = lane >> 3;          // col-group: 4 consecutive cols
    const int ch = lane & 7;          // k-chunk: 16 k-values

    const int col0 = 32 * w + 4 * g;  // lane's 4 cols: col0..col0+3
    const int widx = PAD * (col0 >> 4) + (col0 & 15);
    const int rbase = PAD * ch;       // lane's read chunk base (float idx)

    // one-time: stage readout_w transposed into LDS (round-2 proven)
    for (int e = tid; e < VOC * HID; e += TPB) {
        int v = e >> 7;
        int k = e & (HID - 1);
        rwT[k * VOC + v] = rw_g[e];
    }

    // one-time: W' = pre_scale[k]*W[k][col0+c], packed over k-pairs. 64 VGPRs.
    f32x2 W2[4][8];
#pragma unroll
    for (int q = 0; q < 8; ++q) {
        int k0 = 16 * ch + 2 * q;
        float p0 = pre_s[k0], p1 = pre_s[k0 + 1];
#pragma unroll
        for (int c = 0; c < 4; ++c) {
            f32x2 t;
            t.x = p0 * W_g[k0 * HID + col0 + c];
            t.y = p1 * W_g[(k0 + 1) * HID + col0 + c];
            W2[c][q] = t;
        }
    }
    const float4 bv  = *(const float4*)&b_g[col0];
    const float4 psv = *(const float4*)&post_s[col0];
    const float rbv = (tid < VOC) ? rb_g[tid] : 0.0f;

    // h for lane's 4 cols (replicated across the 8 ch-lanes of group g)
    float4 hc = *(const float4*)&hidden[b * HID + col0];

    // prologue: stage h0 and prime ssb[0] with ss(h0)
    if (ch == 0) *(float4*)&hbuf[0][widx] = hc;
    {
        float ssp = (hc.x * hc.x + hc.y * hc.y) + (hc.z * hc.z + hc.w * hc.w);
        ssp = wave_g_sum(ssp);
        if (lane == 63) ssb[0][w] = ssp;
    }
    __syncthreads();

// one recurrent iteration at read-parity P: reads hbuf[P]+ssb[P], writes
// hbuf[P^1]+ssb[P^1]. rn comes from the PRE-COMPUTED partials (pipelined
// across the barrier) -> rsq/ss-reduce off the post-barrier critical path.
#define ITER(P)                                                                \
    {                                                                          \
        const float4* rb = (const float4*)&hbuf[P][rbase];                     \
        float4 x0 = rb[0], x1 = rb[1], x2 = rb[2], x3 = rb[3];                 \
        const float4 sv = *(const float4*)&ssb[P][0];                          \
        f32x2 a0 = {0,0}, a1 = {0,0}, a2 = {0,0}, a3 = {0,0};                  \
        _Pragma("unroll")                                                      \
        for (int q = 0; q < 8; ++q) {                                          \
            const float4 xq = (q < 2) ? x0 : (q < 4) ? x1 : (q < 6) ? x2 : x3; \
            f32x2 hv;                                                          \
            hv.x = (q & 1) ? xq.z : xq.x;                                      \
            hv.y = (q & 1) ? xq.w : xq.y;                                      \
            a0 = VFMA(hv, W2[0][q], a0);                                       \
            a1 = VFMA(hv, W2[1][q], a1);                                       \
            a2 = VFMA(hv, W2[2][q], a2);                                       \
            a3 = VFMA(hv, W2[3][q], a3);                                       \
        }                                                                      \
        const float rn = rsq_fast(                                             \
            fmaf((sv.x + sv.y) + (sv.z + sv.w), 1.0f / HID, EPSV));            \
        float y0 = a0.x + a0.y, y1 = a1.x + a1.y;                              \
        float y2 = a2.x + a2.y, y3 = a3.x + a3.y;                              \
        BFLY8(y0) BFLY8(y1) BFLY8(y2) BFLY8(y3)                                \
        hc.x += fmaxf(fmaf(y0, rn, ev.x), 0.0f);                               \
        hc.y += fmaxf(fmaf(y1, rn, ev.y), 0.0f);                               \
        hc.z += fmaxf(fmaf(y2, rn, ev.z), 0.0f);                               \
        hc.w += fmaxf(fmaf(y3, rn, ev.w), 0.0f);                               \
        if (ch == 0) *(float4*)&hbuf[P ^ 1][widx] = hc;                        \
        float ssp = (hc.x * hc.x + hc.y * hc.y) + (hc.z * hc.z + hc.w * hc.w); \
        ssp = wave_g_sum(ssp);                                                 \
        if (lane == 63) ssb[P ^ 1][w] = ssp;                                   \
        __syncthreads();                                                       \
    }

    for (int t = 0; t < SLEN; ++t) {
        const int c = chars[b * SLEN + t];
        const float4 er = *(const float4*)&embed_w[c * HID + col0];
        float4 ev;
        ev.x = er.x + bv.x; ev.y = er.y + bv.y;
        ev.z = er.z + bv.z; ev.w = er.w + bv.w;

        for (int it = 0; it < DEPTH / 2; ++it) {
            ITER(0)
            ITER(1)
        }
        // after 500 iters: hc = h_final, hbuf[0] = h_final, ssb[0] = ss(h_final)

        // ---- epilogue: post-norm (replaces h) + readout ----
        {
            const float4 sv = *(const float4*)&ssb[0][0];
            const float ss = (sv.x + sv.y) + (sv.z + sv.w);
            const float rnp = 1.0f / sqrtf(ss * (1.0f / HID) + EPSV);
            hc.x *= rnp * psv.x; hc.y *= rnp * psv.y;
            hc.z *= rnp * psv.z; hc.w *= rnp * psv.w;
            // re-prime ssb[0] with ss(h_carry) for next timestep's ITER(0)
            float ssp = (hc.x * hc.x + hc.y * hc.y) + (hc.z * hc.z + hc.w * hc.w);
            ssp = wave_g_sum(ssp);
            __syncthreads();                 // all waves done reading ssb[0]
            if (ch == 0) *(float4*)&hbuf[0][widx] = hc;  // hpost, padded layout
            if (lane == 63) ssb[0][w] = ssp;
            __syncthreads();                 // visible to readout + next t
        }

        if (tid < VOC) {
            float acc0 = 0.0f, acc1 = 0.0f;
#pragma unroll
            for (int C = 0; C < 8; ++C) {
#pragma unroll
                for (int m4 = 0; m4 < 4; ++m4) {
                    const float4 x = *(const float4*)&hbuf[0][PAD * C + 4 * m4];
                    const int k = 16 * C + 4 * m4;
                    acc0 = fmaf(x.x, rwT[(k + 0) * VOC + tid], acc0);
                    acc1 = fmaf(x.y, rwT[(k + 1) * VOC + tid], acc1);
                    acc0 = fmaf(x.z, rwT[(k + 2) * VOC + tid], acc0);
                    acc1 = fmaf(x.w, rwT[(k + 3) * VOC + tid], acc1);
                }
            }
            out[(b * SLEN + t) * VOC + tid] = acc0 + acc1 + rbv;
        }
        // waves 2-3 run ahead into next t's ITER(0): reads hbuf[0]/ssb[0]
        // (written pre-barrier above); first writes go to hbuf[1]/ssb[1],
        // gated by ITER(0)'s own barrier -> no extra barrier needed.
    }

    if (ch == 0)
        *(float4*)&out[BSZ * SLEN * VOC + b * HID + col0] = hc;

#undef ITER
}

extern "C" void kernel_launch(void* const* d_in, const int* in_sizes, int n_in,
                              void* d_out, int out_size, void* d_ws, size_t ws_size,
                              hipStream_t stream)
{
    const int* chars      = (const int*)d_in[0];
    const float* hidden   = (const float*)d_in[1];
    const float* embed_w  = (const float*)d_in[2];
    const float* W_g      = (const float*)d_in[3];
    const float* b_g      = (const float*)d_in[4];
    const float* pre_s    = (const float*)d_in[5];
    const float* post_s   = (const float*)d_in[6];
    const float* rw_g     = (const float*)d_in[7];
    const float* rb_g     = (const float*)d_in[8];
    float* out            = (float*)d_out;

    rnn_char_lm<<<dim3(BSZ), dim3(TPB), 0, stream>>>(
        chars, hidden, embed_w, W_g, b_g, pre_s, post_s, rw_g, rb_g, out);
}